// Round 4
// baseline (409.047 us; speedup 1.0000x reference)
//
#include <hip/hip_runtime.h>

typedef __attribute__((ext_vector_type(8))) short frag8;     // 8 bf16 = 4 VGPRs
typedef __attribute__((ext_vector_type(4))) float f4;
typedef __attribute__((ext_vector_type(4))) unsigned int u4;
typedef __attribute__((ext_vector_type(2))) float f2;

namespace {
constexpr int T_STEPS = 25;
constexpr int IN_F    = 14;
constexpr int H       = 24;
constexpr int NSTEP   = 13;
constexpr int XSLOTS  = 7;          // x A-frag slots staged per wave (restage at s==7)
// LDS arena (19456 B -> 8 blocks/CU):
//   x:  [0 .. 14336)        per wave 7 slots * 1024 B  (frag: q*256 + e*16)
//   h:  [14336 .. 19456)    per wave 2560 B = {hi,lo} planes * 16 rows * 80 B
//       slot order pi(u) = 2*(u&15) + (u>>4): lane's units (col, col+16) adjacent
//       -> h written as dwords, A-read is contiguous b128 at row pitch 80
constexpr int LDS_HOFF = 14336;
// d_ws layout: shorts [0..24576): B-frags ((dir*3+set)*8+tile)*64+lane, 8 shorts
//   set 0 = Wx_hi (K slots 0..13 = f, 14..27 = f again for x_lo, 28..31 = 0)
//   set 1 = Wh_hi, set 2 = Wh_lo  (K slot k -> unit uh = (k&1) ? (k>>1)+16 : k>>1)
// floats at float-index 12288: bias[dir][128] by gate-row r = g*32+u
}

__device__ __forceinline__ unsigned short bf16_rne(float f) {
    unsigned int u = __float_as_uint(f);
    u += 0x7fff + ((u >> 16) & 1);
    return (unsigned short)(u >> 16);
}
__device__ __forceinline__ float bf16_to_f(unsigned short s) {
    return __uint_as_float(((unsigned int)s) << 16);
}
__device__ __forceinline__ float fast_rcp(float x) { return __builtin_amdgcn_rcpf(x); }
__device__ __forceinline__ float fsig(float x) { return fast_rcp(1.0f + __expf(-x)); }
__device__ __forceinline__ float ftanh(float x) { return 1.0f - 2.0f * fast_rcp(1.0f + __expf(2.0f * x)); }

__global__ void pack_mfma(const float* __restrict__ wif, const float* __restrict__ whf,
                          const float* __restrict__ bif, const float* __restrict__ bhf,
                          const float* __restrict__ wib, const float* __restrict__ whb,
                          const float* __restrict__ bib, const float* __restrict__ bhb,
                          unsigned short* __restrict__ ws)
{
    const int gid = blockIdx.x * 256 + threadIdx.x;
    if (gid < 3072) {
        const int lane = gid & 63;
        const int tile = (gid >> 6) & 7;
        const int set  = (gid >> 9) % 3;
        const int dir  = gid / 1536;
        const int n = lane & 15, q = lane >> 4;
        const int r = tile * 16 + n;             // gate-row: r = g*32 + u
        const int g = r >> 5, u_row = r & 31;
        const bool vrow = (u_row < 24);
        const float* Wx = dir ? wib : wif;
        const float* Wh = dir ? whb : whf;
        const int rowW = g * 24 + (vrow ? u_row : 0);
        unsigned short vals[8];
        #pragma unroll
        for (int j = 0; j < 8; ++j) {
            const int k = q * 8 + j;
            unsigned short o = 0;
            if (vrow) {
                if (set == 0) {
                    const int f = (k < 14) ? k : ((k < 28) ? k - 14 : -1);
                    if (f >= 0) o = bf16_rne(Wx[rowW * IN_F + f]);
                } else {
                    const int uh = (k & 1) ? (k >> 1) + 16 : (k >> 1);
                    if (uh < 24) {
                        const float w = Wh[rowW * H + uh];
                        const unsigned short hi = bf16_rne(w);
                        o = (set == 1) ? hi : bf16_rne(w - bf16_to_f(hi));
                    }
                }
            }
            vals[j] = o;
        }
        unsigned short* d = ws + (size_t)gid * 8;
        #pragma unroll
        for (int j = 0; j < 8; ++j) d[j] = vals[j];
    } else if (gid < 3072 + 256) {
        const int idx = gid - 3072;
        const int dir = idx >> 7, r = idx & 127;
        const int g = r >> 5, u = r & 31;
        const float v = (u < 24)
            ? ((dir ? bib : bif)[g * 24 + u] + (dir ? bhb : bhf)[g * 24 + u]) : 0.0f;
        ((float*)ws)[12288 + dir * 128 + r] = v;
    }
}

__global__ __launch_bounds__(128, 4)
void bilstm_mfma(const float* __restrict__ x, const unsigned short* __restrict__ wpk,
                 const float* __restrict__ head_w, const float* __restrict__ head_b,
                 float* __restrict__ out, int B)
{
    __align__(16) __shared__ unsigned char arena[19456];

    const int tid  = threadIdx.x;
    const int wave = __builtin_amdgcn_readfirstlane(tid >> 6);   // 0 = fwd, 1 = bwd
    const int lane = tid & 63;
    const int q    = lane >> 4;
    const int col  = lane & 15;
    const int b0   = blockIdx.x * 16;

    // resident B-fragments: 3 sets x 8 tiles = 96 regs (+32 acc)
    frag8 Bf[3][8];
    #pragma unroll
    for (int s = 0; s < 3; ++s)
        #pragma unroll
        for (int t = 0; t < 8; ++t)
            Bf[s][t] = ((const frag8*)wpk)[((wave * 3 + s) * 8 + t) * 64 + lane];

    const float* wbias = (const float*)wpk + 12288 + wave * 128;
    float bias_v[8];
    #pragma unroll
    for (int t = 0; t < 8; ++t) bias_v[t] = wbias[t * 16 + col];

    unsigned char* xbase = arena + wave * (XSLOTS * 1024);
    unsigned char* hbase = arena + LDS_HOFF + wave * 2560;

    // stage one (step, elem) x A-frag: slots 0..13 = x_hi(f), 14..27 = x_lo(f), 28..31 = 0
    auto stage_x = [&](int si, int e, int step) {
        const int t = wave ? (T_STEPS - 1 - step) : step;
        const float* xr = x + ((size_t)(b0 + e) * T_STEPS + t) * IN_F;
        float xv[IN_F];
        #pragma unroll
        for (int i = 0; i < 7; ++i) { f2 v = *(const f2*)(xr + 2 * i); xv[2*i] = v.x; xv[2*i+1] = v.y; }
        unsigned short sl[32];
        #pragma unroll
        for (int i = 0; i < IN_F; ++i) {
            const unsigned short hi = bf16_rne(xv[i]);
            sl[i] = hi;
            sl[IN_F + i] = bf16_rne(xv[i] - bf16_to_f(hi));
        }
        sl[28] = sl[29] = sl[30] = sl[31] = 0;
        #pragma unroll
        for (int qq = 0; qq < 4; ++qq) {
            u4 w;
            #pragma unroll
            for (int i = 0; i < 4; ++i)
                w[i] = (unsigned int)sl[qq*8 + 2*i] | ((unsigned int)sl[qq*8 + 2*i + 1] << 16);
            *(u4*)(xbase + si * 1024 + qq * 256 + e * 16) = w;
        }
    };

    // prefill steps 0..6 (own region only: no barrier needed, in-wave ordering)
    for (int rr = lane; rr < XSLOTS * 16; rr += 64) stage_x(rr >> 4, rr & 15, rr >> 4);

    float c_st[2][4];
    #pragma unroll
    for (int p = 0; p < 2; ++p)
        #pragma unroll
        for (int r = 0; r < 4; ++r) c_st[p][r] = 0.0f;

    const unsigned char* xrd = xbase + q * 256 + col * 16;
    const unsigned char* hrd = hbase + col * 80 + q * 16;    // A-frag: m=col, k=q*8+j
    unsigned char* hwr = hbase + col * 4;                    // dword {u=col, u=col+16}

    // activations + h write: tiles (i,f,g,o) = (p, 2+p, 4+p, 6+p); m = q*4+r
    auto gates_and_store = [&](f4* acc) {
        #pragma unroll
        for (int r = 0; r < 4; ++r) {
            unsigned int whi = 0, wlo = 0;
            #pragma unroll
            for (int p = 0; p < 2; ++p) {
                const float iv = acc[0 + p][r], fv = acc[2 + p][r];
                const float gv = acc[4 + p][r], ov = acc[6 + p][r];
                const float ig = fsig(iv), fg = fsig(fv), gg = ftanh(gv), og = fsig(ov);
                const float cn = fg * c_st[p][r] + ig * gg;
                c_st[p][r] = cn;
                const float h = og * ftanh(cn);
                const unsigned short hh = bf16_rne(h);
                const unsigned short hl = bf16_rne(h - bf16_to_f(hh));
                whi |= (unsigned int)hh << (16 * p);
                wlo |= (unsigned int)hl << (16 * p);
            }
            *(unsigned int*)(hwr + (q * 4 + r) * 80)        = whi;
            *(unsigned int*)(hwr + (q * 4 + r) * 80 + 1280) = wlo;
        }
    };

    // ---- step 0 (h = 0: x-product + bias only) ----
    {
        const frag8 Ax = *(const frag8*)(xrd);
        f4 acc[8];
        #pragma unroll
        for (int t = 0; t < 8; ++t) { const float b = bias_v[t]; acc[t] = (f4){b, b, b, b}; }
        #pragma unroll
        for (int t = 0; t < 8; ++t)
            acc[t] = __builtin_amdgcn_mfma_f32_16x16x32_bf16(Ax, Bf[0][t], acc[t], 0, 0, 0);
        gates_and_store(acc);
    }

    // ---- steps 1..12, no barriers (wave-private LDS, in-order DS ops) ----
    #pragma unroll 1
    for (int s = 1; s < NSTEP; ++s) {
        if (s == XSLOTS) {   // restage steps 7..12 into slots 0..5 (own region)
            for (int rr = lane; rr < (NSTEP - XSLOTS) * 16; rr += 64)
                stage_x(rr >> 4, rr & 15, XSLOTS + (rr >> 4));
        }
        const int xs = (s < XSLOTS) ? s : s - XSLOTS;
        const frag8 Ax  = *(const frag8*)(xrd + xs * 1024);
        const frag8 Ahh = *(const frag8*)(hrd);
        const frag8 Ahl = *(const frag8*)(hrd + 1280);

        f4 acc[8];
        #pragma unroll
        for (int t = 0; t < 8; ++t) { const float b = bias_v[t]; acc[t] = (f4){b, b, b, b}; }
        #pragma unroll
        for (int t = 0; t < 8; ++t) {
            acc[t] = __builtin_amdgcn_mfma_f32_16x16x32_bf16(Ax,  Bf[0][t], acc[t], 0, 0, 0);
            acc[t] = __builtin_amdgcn_mfma_f32_16x16x32_bf16(Ahh, Bf[1][t], acc[t], 0, 0, 0);
            acc[t] = __builtin_amdgcn_mfma_f32_16x16x32_bf16(Ahl, Bf[1][t], acc[t], 0, 0, 0);
            acc[t] = __builtin_amdgcn_mfma_f32_16x16x32_bf16(Ahh, Bf[2][t], acc[t], 0, 0, 0);
        }
        gates_and_store(acc);
    }

    __syncthreads();   // only cross-wave point: head reads both directions' h

    if (tid < 64) {
        const int e = tid >> 2, cls = tid & 3;
        float acc = head_b[cls];
        #pragma unroll
        for (int u = 0; u < H; ++u) {
            const int so = 2 * ((u & 15) * 2 + (u >> 4));   // byte offset of slot pi(u)
            const unsigned char* hf0 = arena + LDS_HOFF + e * 80 + so;
            const float hf = bf16_to_f(*(const unsigned short*)(hf0))
                           + bf16_to_f(*(const unsigned short*)(hf0 + 1280));
            const float hb = bf16_to_f(*(const unsigned short*)(hf0 + 2560))
                           + bf16_to_f(*(const unsigned short*)(hf0 + 2560 + 1280));
            acc += hf * head_w[cls * 2 * H + u] + hb * head_w[cls * 2 * H + H + u];
        }
        out[(size_t)b0 * 4 + tid] = acc;
    }
}

extern "C" void kernel_launch(void* const* d_in, const int* in_sizes, int n_in,
                              void* d_out, int out_size, void* d_ws, size_t ws_size,
                              hipStream_t stream)
{
    const float* x      = (const float*)d_in[0];
    const float* w_ih_f = (const float*)d_in[1];
    const float* w_hh_f = (const float*)d_in[2];
    const float* b_ih_f = (const float*)d_in[3];
    const float* b_hh_f = (const float*)d_in[4];
    const float* w_ih_b = (const float*)d_in[5];
    const float* w_hh_b = (const float*)d_in[6];
    const float* b_ih_b = (const float*)d_in[7];
    const float* b_hh_b = (const float*)d_in[8];
    const float* head_w = (const float*)d_in[9];
    const float* head_b = (const float*)d_in[10];
    float* out = (float*)d_out;
    unsigned short* ws = (unsigned short*)d_ws;

    const int B = in_sizes[0] / (T_STEPS * IN_F);

    hipLaunchKernelGGL(pack_mfma, dim3(13), dim3(256), 0, stream,
                       w_ih_f, w_hh_f, b_ih_f, b_hh_f,
                       w_ih_b, w_hh_b, b_ih_b, b_hh_b, ws);
    hipLaunchKernelGGL(bilstm_mfma, dim3((B + 15) / 16), dim3(128), 0, stream,
                       x, ws, head_w, head_b, out, B);
}

// Round 5
// 218.019 us; speedup vs baseline: 1.8762x; 1.8762x over previous
//
#include <hip/hip_runtime.h>

typedef __attribute__((ext_vector_type(8))) short frag8;     // 8 bf16 = 4 VGPRs
typedef __attribute__((ext_vector_type(4))) float f4;
typedef __attribute__((ext_vector_type(4))) unsigned int u4;
typedef __attribute__((ext_vector_type(2))) float f2;

namespace {
constexpr int T_STEPS = 25;
constexpr int IN_F    = 14;
constexpr int H       = 24;
constexpr int NSTEP   = 13;
constexpr int XSLOTS  = 7;          // x A-frag slots staged per wave (restage at s==7)
// LDS arena (19456 B):
//   x:  [0 .. 14336)        per wave 7 slots * 1024 B  (frag: q*256 + e*16)
//   h:  [14336 .. 19456)    per wave 2560 B = {hi,lo} planes * 16 rows * 80 B
//       slot order pi(u) = 2*(u&15) + (u>>4): lane's units (col, col+16) adjacent
constexpr int LDS_HOFF = 14336;
// d_ws layout: shorts [0..16384): B-frags ((dir*2+set)*8+tile)*64+lane, 8 shorts
//   set 0 = Wx_hi: K rows 0..13 = Wx_hi[f], 14..27 = Wx_hi[f-14] (x_lo slots),
//           row 28 = bias_hi, row 29 = bias_lo, 30..31 = 0
//   set 1 = Wh_hi: K row k -> unit uh = (k&1) ? (k>>1)+16 : (k>>1), 0 if uh>=24
}

__device__ __forceinline__ unsigned short bf16_rne(float f) {
    unsigned int u = __float_as_uint(f);
    u += 0x7fff + ((u >> 16) & 1);
    return (unsigned short)(u >> 16);
}
__device__ __forceinline__ float bf16_to_f(unsigned short s) {
    return __uint_as_float(((unsigned int)s) << 16);
}
__device__ __forceinline__ float fast_rcp(float x) { return __builtin_amdgcn_rcpf(x); }
__device__ __forceinline__ float fsig(float x) { return fast_rcp(1.0f + __expf(-x)); }
__device__ __forceinline__ float ftanh(float x) { return 1.0f - 2.0f * fast_rcp(1.0f + __expf(2.0f * x)); }

__global__ void pack_mfma(const float* __restrict__ wif, const float* __restrict__ whf,
                          const float* __restrict__ bif, const float* __restrict__ bhf,
                          const float* __restrict__ wib, const float* __restrict__ whb,
                          const float* __restrict__ bib, const float* __restrict__ bhb,
                          unsigned short* __restrict__ ws)
{
    const int gid = blockIdx.x * 256 + threadIdx.x;
    if (gid >= 2048) return;
    const int lane = gid & 63;
    const int tile = (gid >> 6) & 7;
    const int set  = (gid >> 9) & 1;
    const int dir  = (gid >> 10) & 1;
    const int n = lane & 15, q = lane >> 4;
    const int r = tile * 16 + n;             // gate-row: r = g*32 + u
    const int g = r >> 5, u_row = r & 31;
    const bool vrow = (u_row < 24);
    const float* Wx = dir ? wib : wif;
    const float* Wh = dir ? whb : whf;
    const float* bi = dir ? bib : bif;
    const float* bh = dir ? bhb : bhf;
    const int rowW = g * 24 + (vrow ? u_row : 0);
    unsigned short vals[8];
    #pragma unroll
    for (int j = 0; j < 8; ++j) {
        const int k = q * 8 + j;
        unsigned short o = 0;
        if (vrow) {
            if (set == 0) {
                if (k < 28) {
                    const int f = (k < 14) ? k : k - 14;
                    o = bf16_rne(Wx[rowW * IN_F + f]);
                } else if (k < 30) {
                    const float b = bi[rowW] + bh[rowW];
                    const unsigned short hi = bf16_rne(b);
                    o = (k == 28) ? hi : bf16_rne(b - bf16_to_f(hi));
                }
            } else {
                const int uh = (k & 1) ? (k >> 1) + 16 : (k >> 1);
                if (uh < 24) o = bf16_rne(Wh[rowW * H + uh]);
            }
        }
        vals[j] = o;
    }
    unsigned short* d = ws + (size_t)gid * 8;
    #pragma unroll
    for (int j = 0; j < 8; ++j) d[j] = vals[j];
}

__global__ __launch_bounds__(128, 3)
void bilstm_mfma(const float* __restrict__ x, const unsigned short* __restrict__ wpk,
                 const float* __restrict__ head_w, const float* __restrict__ head_b,
                 float* __restrict__ out, int B)
{
    __align__(16) __shared__ unsigned char arena[19456];

    const int tid  = threadIdx.x;
    const int wave = __builtin_amdgcn_readfirstlane(tid >> 6);   // 0 = fwd, 1 = bwd
    const int lane = tid & 63;
    const int q    = lane >> 4;
    const int col  = lane & 15;
    const int b0   = blockIdx.x * 16;

    // resident B-fragments: 2 sets x 8 tiles = 64 VGPRs (+32 acc)
    frag8 Bf[2][8];
    #pragma unroll
    for (int s = 0; s < 2; ++s)
        #pragma unroll
        for (int t = 0; t < 8; ++t)
            Bf[s][t] = ((const frag8*)wpk)[((wave * 2 + s) * 8 + t) * 64 + lane];

    unsigned char* xbase = arena + wave * (XSLOTS * 1024);
    unsigned char* hbase = arena + LDS_HOFF + wave * 2560;

    // stage one (step, elem) x A-frag: slots 0..13 = x_hi, 14..27 = x_lo,
    // 28..29 = 1.0 (bias rows in B), 30..31 = 0
    auto stage_x = [&](int si, int e, int step) {
        const int t = wave ? (T_STEPS - 1 - step) : step;
        const float* xr = x + ((size_t)(b0 + e) * T_STEPS + t) * IN_F;
        float xv[IN_F];
        #pragma unroll
        for (int i = 0; i < 7; ++i) { f2 v = *(const f2*)(xr + 2 * i); xv[2*i] = v.x; xv[2*i+1] = v.y; }
        unsigned short sl[32];
        #pragma unroll
        for (int i = 0; i < IN_F; ++i) {
            const unsigned short hi = bf16_rne(xv[i]);
            sl[i] = hi;
            sl[IN_F + i] = bf16_rne(xv[i] - bf16_to_f(hi));
        }
        sl[28] = 0x3F80; sl[29] = 0x3F80; sl[30] = 0; sl[31] = 0;   // 1.0, 1.0, 0, 0
        #pragma unroll
        for (int qq = 0; qq < 4; ++qq) {
            u4 w;
            #pragma unroll
            for (int i = 0; i < 4; ++i)
                w[i] = (unsigned int)sl[qq*8 + 2*i] | ((unsigned int)sl[qq*8 + 2*i + 1] << 16);
            *(u4*)(xbase + si * 1024 + qq * 256 + e * 16) = w;
        }
    };

    // prefill steps 0..6 (own region only: no barrier needed, in-wave ordering)
    for (int rr = lane; rr < XSLOTS * 16; rr += 64) stage_x(rr >> 4, rr & 15, rr >> 4);

    float c_st[2][4];
    #pragma unroll
    for (int p = 0; p < 2; ++p)
        #pragma unroll
        for (int r = 0; r < 4; ++r) c_st[p][r] = 0.0f;

    const unsigned char* xrd = xbase + q * 256 + col * 16;
    const unsigned char* hrd = hbase + col * 80 + q * 16;    // A-frag: m=col, k=q*8+j
    unsigned char* hwr = hbase + col * 4;                    // dword {u=col, u=col+16}

    // activations + h write: tiles (i,f,g,o) = (p, 2+p, 4+p, 6+p); m = q*4+r
    auto gates_and_store = [&](f4* acc) {
        #pragma unroll
        for (int r = 0; r < 4; ++r) {
            unsigned int whi = 0, wlo = 0;
            #pragma unroll
            for (int p = 0; p < 2; ++p) {
                const float iv = acc[0 + p][r], fv = acc[2 + p][r];
                const float gv = acc[4 + p][r], ov = acc[6 + p][r];
                const float ig = fsig(iv), fg = fsig(fv), gg = ftanh(gv), og = fsig(ov);
                const float cn = fg * c_st[p][r] + ig * gg;
                c_st[p][r] = cn;
                const float h = og * ftanh(cn);
                const unsigned short hh = bf16_rne(h);
                const unsigned short hl = bf16_rne(h - bf16_to_f(hh));
                whi |= (unsigned int)hh << (16 * p);
                wlo |= (unsigned int)hl << (16 * p);
            }
            *(unsigned int*)(hwr + (q * 4 + r) * 80)        = whi;
            *(unsigned int*)(hwr + (q * 4 + r) * 80 + 1280) = wlo;
        }
    };

    // ---- step 0 (h = 0: x-product + bias rows only) ----
    {
        const frag8 Ax = *(const frag8*)(xrd);
        f4 acc[8];
        #pragma unroll
        for (int t = 0; t < 8; ++t) acc[t] = (f4){0.f, 0.f, 0.f, 0.f};
        #pragma unroll
        for (int t = 0; t < 8; ++t)
            acc[t] = __builtin_amdgcn_mfma_f32_16x16x32_bf16(Ax, Bf[0][t], acc[t], 0, 0, 0);
        gates_and_store(acc);
    }

    // ---- steps 1..12, no barriers (wave-private LDS, in-order DS ops) ----
    #pragma unroll 1
    for (int s = 1; s < NSTEP; ++s) {
        if (s == XSLOTS) {   // restage steps 7..12 into slots 0..5 (own region)
            for (int rr = lane; rr < (NSTEP - XSLOTS) * 16; rr += 64)
                stage_x(rr >> 4, rr & 15, XSLOTS + (rr >> 4));
        }
        const int xs = (s < XSLOTS) ? s : s - XSLOTS;
        const frag8 Ax  = *(const frag8*)(xrd + xs * 1024);
        const frag8 Ahh = *(const frag8*)(hrd);
        const frag8 Ahl = *(const frag8*)(hrd + 1280);

        f4 acc[8];
        #pragma unroll
        for (int t = 0; t < 8; ++t) acc[t] = (f4){0.f, 0.f, 0.f, 0.f};
        #pragma unroll
        for (int t = 0; t < 8; ++t) {
            acc[t] = __builtin_amdgcn_mfma_f32_16x16x32_bf16(Ax,  Bf[0][t], acc[t], 0, 0, 0);
            acc[t] = __builtin_amdgcn_mfma_f32_16x16x32_bf16(Ahh, Bf[1][t], acc[t], 0, 0, 0);
            acc[t] = __builtin_amdgcn_mfma_f32_16x16x32_bf16(Ahl, Bf[1][t], acc[t], 0, 0, 0);
        }
        gates_and_store(acc);
    }

    __syncthreads();   // only cross-wave point: head reads both directions' h

    if (tid < 64) {
        const int e = tid >> 2, cls = tid & 3;
        float acc = head_b[cls];
        #pragma unroll
        for (int u = 0; u < H; ++u) {
            const int so = 2 * ((u & 15) * 2 + (u >> 4));   // byte offset of slot pi(u)
            const unsigned char* hf0 = arena + LDS_HOFF + e * 80 + so;
            const float hf = bf16_to_f(*(const unsigned short*)(hf0))
                           + bf16_to_f(*(const unsigned short*)(hf0 + 1280));
            const float hb = bf16_to_f(*(const unsigned short*)(hf0 + 2560))
                           + bf16_to_f(*(const unsigned short*)(hf0 + 2560 + 1280));
            acc += hf * head_w[cls * 2 * H + u] + hb * head_w[cls * 2 * H + H + u];
        }
        out[(size_t)b0 * 4 + tid] = acc;
    }
}

extern "C" void kernel_launch(void* const* d_in, const int* in_sizes, int n_in,
                              void* d_out, int out_size, void* d_ws, size_t ws_size,
                              hipStream_t stream)
{
    const float* x      = (const float*)d_in[0];
    const float* w_ih_f = (const float*)d_in[1];
    const float* w_hh_f = (const float*)d_in[2];
    const float* b_ih_f = (const float*)d_in[3];
    const float* b_hh_f = (const float*)d_in[4];
    const float* w_ih_b = (const float*)d_in[5];
    const float* w_hh_b = (const float*)d_in[6];
    const float* b_ih_b = (const float*)d_in[7];
    const float* b_hh_b = (const float*)d_in[8];
    const float* head_w = (const float*)d_in[9];
    const float* head_b = (const float*)d_in[10];
    float* out = (float*)d_out;
    unsigned short* ws = (unsigned short*)d_ws;

    const int B = in_sizes[0] / (T_STEPS * IN_F);

    hipLaunchKernelGGL(pack_mfma, dim3(8), dim3(256), 0, stream,
                       w_ih_f, w_hh_f, b_ih_f, b_hh_f,
                       w_ih_b, w_hh_b, b_ih_b, b_hh_b, ws);
    hipLaunchKernelGGL(bilstm_mfma, dim3((B + 15) / 16), dim3(128), 0, stream,
                       x, ws, head_w, head_b, out, B);
}

// Round 6
// 201.616 us; speedup vs baseline: 2.0288x; 1.0814x over previous
//
#include <hip/hip_runtime.h>

typedef __attribute__((ext_vector_type(8))) short frag8;     // 8 bf16 = 4 VGPRs
typedef __attribute__((ext_vector_type(4))) float f4;
typedef __attribute__((ext_vector_type(4))) unsigned int u4;
typedef __attribute__((ext_vector_type(2))) float f2;

namespace {
constexpr int T_STEPS = 25;
constexpr int IN_F    = 14;
constexpr int H       = 24;
constexpr int NSTEP   = 13;
constexpr int XSLOTS  = 7;          // x A-frag slots staged per wave (restage at s==7)
// LDS arena (19456 B):
//   x:  [0 .. 14336)        per wave 7 slots * 1024 B  (frag: q*256 + e*16)
//   h:  [14336 .. 19456)    per wave 2560 B = {hi,lo} planes * 16 rows * 80 B
//       slot order pi(u) = 2*(u&15) + (u>>4): lane's units (col, col+16) adjacent
constexpr int LDS_HOFF = 14336;
// d_ws layout: shorts [0..16384): B-frags ((dir*2+set)*8+tile)*64+lane, 8 shorts
//   Weights/biases PRE-SCALED per gate: i,f,o rows * (-log2e), g rows * (2*log2e)
//   so activations use exp2 directly with no scale-mul.
//   set 0 = Wx: K 0..13 = Wx[f], 14..27 = Wx[f-14] (x_lo slots),
//           K 28 = bias_hi, 29 = bias_lo, 30..31 = 0
//   set 1 = Wh: K k -> unit uh = (k&1) ? (k>>1)+16 : (k>>1), 0 if uh>=24
constexpr float LOG2E  = 1.4426950408889634f;
constexpr float TWOLOG2E = 2.8853900817779268f;
}

#if __has_builtin(__builtin_amdgcn_exp2f)
#define EXP2F(v) __builtin_amdgcn_exp2f(v)
#else
#define EXP2F(v) __expf(0.6931471805599453f * (v))
#endif

__device__ __forceinline__ unsigned short bf16_rne(float f) {
    unsigned int u = __float_as_uint(f);
    u += 0x7fff + ((u >> 16) & 1);
    return (unsigned short)(u >> 16);
}
__device__ __forceinline__ float bf16_to_f(unsigned short s) {
    return __uint_as_float(((unsigned int)s) << 16);
}
__device__ __forceinline__ float fast_rcp(float x) { return __builtin_amdgcn_rcpf(x); }

__global__ void pack_mfma(const float* __restrict__ wif, const float* __restrict__ whf,
                          const float* __restrict__ bif, const float* __restrict__ bhf,
                          const float* __restrict__ wib, const float* __restrict__ whb,
                          const float* __restrict__ bib, const float* __restrict__ bhb,
                          unsigned short* __restrict__ ws)
{
    const int gid = blockIdx.x * 256 + threadIdx.x;
    if (gid >= 2048) return;
    const int lane = gid & 63;
    const int tile = (gid >> 6) & 7;
    const int set  = (gid >> 9) & 1;
    const int dir  = (gid >> 10) & 1;
    const int n = lane & 15, q = lane >> 4;
    const int r = tile * 16 + n;             // gate-row: r = g*32 + u
    const int g = r >> 5, u_row = r & 31;
    const bool vrow = (u_row < 24);
    const float* Wx = dir ? wib : wif;
    const float* Wh = dir ? whb : whf;
    const float* bi = dir ? bib : bif;
    const float* bh = dir ? bhb : bhf;
    const int rowW = g * 24 + (vrow ? u_row : 0);
    const float scale = (g == 2) ? TWOLOG2E : -LOG2E;   // g-gate vs i,f,o
    unsigned short vals[8];
    #pragma unroll
    for (int j = 0; j < 8; ++j) {
        const int k = q * 8 + j;
        unsigned short o = 0;
        if (vrow) {
            if (set == 0) {
                if (k < 28) {
                    const int f = (k < 14) ? k : k - 14;
                    o = bf16_rne(scale * Wx[rowW * IN_F + f]);
                } else if (k < 30) {
                    const float b = scale * (bi[rowW] + bh[rowW]);
                    const unsigned short hi = bf16_rne(b);
                    o = (k == 28) ? hi : bf16_rne(b - bf16_to_f(hi));
                }
            } else {
                const int uh = (k & 1) ? (k >> 1) + 16 : (k >> 1);
                if (uh < 24) o = bf16_rne(scale * Wh[rowW * H + uh]);
            }
        }
        vals[j] = o;
    }
    unsigned short* d = ws + (size_t)gid * 8;
    #pragma unroll
    for (int j = 0; j < 8; ++j) d[j] = vals[j];
}

__global__ __launch_bounds__(128, 3)
void bilstm_mfma(const float* __restrict__ x, const unsigned short* __restrict__ wpk,
                 const float* __restrict__ head_w, const float* __restrict__ head_b,
                 float* __restrict__ out, int B)
{
    __align__(16) __shared__ unsigned char arena[19456];

    const int tid  = threadIdx.x;
    const int wave = __builtin_amdgcn_readfirstlane(tid >> 6);   // 0 = fwd, 1 = bwd
    const int lane = tid & 63;
    const int q    = lane >> 4;
    const int col  = lane & 15;
    const int b0   = blockIdx.x * 16;

    // resident B-fragments: 2 sets x 8 tiles
    frag8 Bf[2][8];
    #pragma unroll
    for (int s = 0; s < 2; ++s)
        #pragma unroll
        for (int t = 0; t < 8; ++t)
            Bf[s][t] = ((const frag8*)wpk)[((wave * 2 + s) * 8 + t) * 64 + lane];

    unsigned char* xbase = arena + wave * (XSLOTS * 1024);
    unsigned char* hbase = arena + LDS_HOFF + wave * 2560;

    // stage one (step, elem) x A-frag via truncation hi/lo split + v_perm packing.
    // slots 0..13 = x_hi (top-16 trunc), 14..27 = x_lo (residual, trunc),
    // 28..29 = 1.0 (bias rows in B), 30..31 = 0
    auto stage_x = [&](int si, int e, int step) {
        const int t = wave ? (T_STEPS - 1 - step) : step;
        const float* xr = x + ((size_t)(b0 + e) * T_STEPS + t) * IN_F;
        unsigned int xu[IN_F];
        #pragma unroll
        for (int i = 0; i < 7; ++i) {
            f2 v = *(const f2*)(xr + 2 * i);
            xu[2*i] = __float_as_uint(v.x); xu[2*i+1] = __float_as_uint(v.y);
        }
        unsigned int lo[IN_F];
        #pragma unroll
        for (int i = 0; i < IN_F; ++i)
            lo[i] = __float_as_uint(__uint_as_float(xu[i])
                                    - __uint_as_float(xu[i] & 0xFFFF0000u));
        unsigned int w[16];
        #pragma unroll
        for (int i = 0; i < 7; ++i)
            w[i] = __builtin_amdgcn_perm(xu[2*i+1], xu[2*i], 0x07060302u);   // {hi16,hi16}
        w[7] = __builtin_amdgcn_perm(lo[1], lo[0], 0x07060302u);
        #pragma unroll
        for (int i = 0; i < 6; ++i)
            w[8 + i] = __builtin_amdgcn_perm(lo[2*i+3], lo[2*i+2], 0x07060302u);
        w[14] = 0x3F803F80u;   // bf16 {1.0, 1.0} -> bias rows
        w[15] = 0u;
        #pragma unroll
        for (int qq = 0; qq < 4; ++qq)
            *(u4*)(xbase + si * 1024 + qq * 256 + e * 16) =
                (u4){w[qq*4], w[qq*4+1], w[qq*4+2], w[qq*4+3]};
    };

    // prefill steps 0..6 (own region only: no barrier needed, in-wave ordering)
    for (int rr = lane; rr < XSLOTS * 16; rr += 64) stage_x(rr >> 4, rr & 15, rr >> 4);

    float c_st[2][4];
    #pragma unroll
    for (int p = 0; p < 2; ++p)
        #pragma unroll
        for (int r = 0; r < 4; ++r) c_st[p][r] = 0.0f;

    const unsigned char* xrd = xbase + q * 256 + col * 16;
    const unsigned char* hrd = hbase + col * 80 + q * 16;    // A-frag: m=col, k=q*8+j
    unsigned char* hwr = hbase + col * 4;                    // dword {u=col, u=col+16}

    // activations + h write. Pre-scaled accs: i,f,o hold -a*log2e; g holds 2a*log2e.
    // tiles (i,f,g,o) = (p, 2+p, 4+p, 6+p); m = q*4+r
    auto gates_and_store = [&](f4* acc) {
        #pragma unroll
        for (int r = 0; r < 4; ++r) {
            float hv[2], hl[2];
            #pragma unroll
            for (int p = 0; p < 2; ++p) {
                const float ig = fast_rcp(1.0f + EXP2F(acc[0 + p][r]));
                const float fg = fast_rcp(1.0f + EXP2F(acc[2 + p][r]));
                const float gg = 1.0f - 2.0f * fast_rcp(1.0f + EXP2F(acc[4 + p][r]));
                const float og = fast_rcp(1.0f + EXP2F(acc[6 + p][r]));
                const float cn = fg * c_st[p][r] + ig * gg;
                c_st[p][r] = cn;
                const float tc = 1.0f - 2.0f * fast_rcp(1.0f + EXP2F(TWOLOG2E * cn));
                const float h  = og * tc;
                const float hh = __uint_as_float(__float_as_uint(h) & 0xFFFF0000u);
                hv[p] = h;
                hl[p] = h - hh;
            }
            const unsigned int whi = __builtin_amdgcn_perm(
                __float_as_uint(hv[1]), __float_as_uint(hv[0]), 0x07060302u);
            const unsigned int wlo = __builtin_amdgcn_perm(
                __float_as_uint(hl[1]), __float_as_uint(hl[0]), 0x07060302u);
            *(unsigned int*)(hwr + (q * 4 + r) * 80)        = whi;
            *(unsigned int*)(hwr + (q * 4 + r) * 80 + 1280) = wlo;
        }
    };

    // ---- step 0 (h = 0: x-product + bias rows only) ----
    {
        const frag8 Ax = *(const frag8*)(xrd);
        f4 acc[8];
        #pragma unroll
        for (int t = 0; t < 8; ++t) acc[t] = (f4){0.f, 0.f, 0.f, 0.f};
        #pragma unroll
        for (int t = 0; t < 8; ++t)
            acc[t] = __builtin_amdgcn_mfma_f32_16x16x32_bf16(Ax, Bf[0][t], acc[t], 0, 0, 0);
        gates_and_store(acc);
    }

    // ---- steps 1..12, no barriers (wave-private LDS, in-order DS ops) ----
    #pragma unroll 1
    for (int s = 1; s < NSTEP; ++s) {
        if (s == XSLOTS) {   // restage steps 7..12 into slots 0..5 (own region)
            for (int rr = lane; rr < (NSTEP - XSLOTS) * 16; rr += 64)
                stage_x(rr >> 4, rr & 15, XSLOTS + (rr >> 4));
        }
        const int xs = (s < XSLOTS) ? s : s - XSLOTS;
        const frag8 Ax  = *(const frag8*)(xrd + xs * 1024);
        const frag8 Ahh = *(const frag8*)(hrd);
        const frag8 Ahl = *(const frag8*)(hrd + 1280);

        f4 acc[8];
        #pragma unroll
        for (int t = 0; t < 8; ++t) acc[t] = (f4){0.f, 0.f, 0.f, 0.f};
        #pragma unroll
        for (int t = 0; t < 8; ++t) {
            acc[t] = __builtin_amdgcn_mfma_f32_16x16x32_bf16(Ax,  Bf[0][t], acc[t], 0, 0, 0);
            acc[t] = __builtin_amdgcn_mfma_f32_16x16x32_bf16(Ahh, Bf[1][t], acc[t], 0, 0, 0);
            acc[t] = __builtin_amdgcn_mfma_f32_16x16x32_bf16(Ahl, Bf[1][t], acc[t], 0, 0, 0);
        }
        gates_and_store(acc);
    }

    __syncthreads();   // only cross-wave point: head reads both directions' h

    if (tid < 64) {
        const int e = tid >> 2, cls = tid & 3;
        float acc = head_b[cls];
        #pragma unroll
        for (int u = 0; u < H; ++u) {
            const int so = 2 * ((u & 15) * 2 + (u >> 4));   // byte offset of slot pi(u)
            const unsigned char* hf0 = arena + LDS_HOFF + e * 80 + so;
            const float hf = bf16_to_f(*(const unsigned short*)(hf0))
                           + bf16_to_f(*(const unsigned short*)(hf0 + 1280));
            const float hb = bf16_to_f(*(const unsigned short*)(hf0 + 2560))
                           + bf16_to_f(*(const unsigned short*)(hf0 + 2560 + 1280));
            acc += hf * head_w[cls * 2 * H + u] + hb * head_w[cls * 2 * H + H + u];
        }
        out[(size_t)b0 * 4 + tid] = acc;
    }
}

extern "C" void kernel_launch(void* const* d_in, const int* in_sizes, int n_in,
                              void* d_out, int out_size, void* d_ws, size_t ws_size,
                              hipStream_t stream)
{
    const float* x      = (const float*)d_in[0];
    const float* w_ih_f = (const float*)d_in[1];
    const float* w_hh_f = (const float*)d_in[2];
    const float* b_ih_f = (const float*)d_in[3];
    const float* b_hh_f = (const float*)d_in[4];
    const float* w_ih_b = (const float*)d_in[5];
    const float* w_hh_b = (const float*)d_in[6];
    const float* b_ih_b = (const float*)d_in[7];
    const float* b_hh_b = (const float*)d_in[8];
    const float* head_w = (const float*)d_in[9];
    const float* head_b = (const float*)d_in[10];
    float* out = (float*)d_out;
    unsigned short* ws = (unsigned short*)d_ws;

    const int B = in_sizes[0] / (T_STEPS * IN_F);

    hipLaunchKernelGGL(pack_mfma, dim3(8), dim3(256), 0, stream,
                       w_ih_f, w_hh_f, b_ih_f, b_hh_f,
                       w_ih_b, w_hh_b, b_ih_b, b_hh_b, ws);
    hipLaunchKernelGGL(bilstm_mfma, dim3((B + 15) / 16), dim3(128), 0, stream,
                       x, ws, head_w, head_b, out, B);
}

// Round 7
// 197.953 us; speedup vs baseline: 2.0664x; 1.0185x over previous
//
#include <hip/hip_runtime.h>

typedef __attribute__((ext_vector_type(8))) short frag8;     // 8 bf16 = 4 VGPRs
typedef __attribute__((ext_vector_type(4))) float f4;
typedef __attribute__((ext_vector_type(4))) unsigned int u4;
typedef __attribute__((ext_vector_type(2))) float f2;

namespace {
constexpr int T_STEPS = 25;
constexpr int IN_F    = 14;
constexpr int H       = 24;
constexpr int NSTEP   = 13;
constexpr int WAVE_LDS = NSTEP * 1024;   // 13312 B per wave: x staging only
// MFMA role swap vs r6: weights are the A operand (M = gate-rows), activations
// are the B operand (N = batch). C/D: col = batch, row = gate-row-in-tile.
// h k-slot order u(k) = (k&7)<4 ? 4*(k>>3)+(k&7) : 16+4*(k>>3)+((k&7)-4):
// lane (q,col)'s OUTPUT h-units {4q+r, 16+4q+r} == its own B-frag k-slots
// -> recurrent h stays in registers, no LDS round-trip.
// d_ws: shorts [0..16384): frags ((dir*2+set)*8+tile)*64+lane, 8 shorts.
//   Pre-scaled per gate: i,f,o rows * (-log2e), g rows * (2*log2e).
//   set 0 = Wx: k 0..13 = Wx[f] (x_hi), 14..27 = Wx[f-14] (x_lo),
//           k 28 = bias_hi, 29 = bias_lo, 30..31 = 0
//   set 1 = Wh: k -> unit u(k) above, 0 if u >= 24
constexpr float LOG2E    = 1.4426950408889634f;
constexpr float TWOLOG2E = 2.8853900817779268f;
}

#if __has_builtin(__builtin_amdgcn_exp2f)
#define EXP2F(v) __builtin_amdgcn_exp2f(v)
#else
#define EXP2F(v) __expf(0.6931471805599453f * (v))
#endif

__device__ __forceinline__ unsigned short bf16_rne(float f) {
    unsigned int u = __float_as_uint(f);
    u += 0x7fff + ((u >> 16) & 1);
    return (unsigned short)(u >> 16);
}
__device__ __forceinline__ float bf16_to_f(unsigned short s) {
    return __uint_as_float(((unsigned int)s) << 16);
}
__device__ __forceinline__ float fast_rcp(float x) { return __builtin_amdgcn_rcpf(x); }

__global__ void pack_mfma(const float* __restrict__ wif, const float* __restrict__ whf,
                          const float* __restrict__ bif, const float* __restrict__ bhf,
                          const float* __restrict__ wib, const float* __restrict__ whb,
                          const float* __restrict__ bib, const float* __restrict__ bhb,
                          unsigned short* __restrict__ ws)
{
    const int gid = blockIdx.x * 256 + threadIdx.x;
    if (gid >= 2048) return;
    const int lane = gid & 63;
    const int tile = (gid >> 6) & 7;
    const int set  = (gid >> 9) & 1;
    const int dir  = (gid >> 10) & 1;
    const int n = lane & 15, q = lane >> 4;
    const int r = tile * 16 + n;             // gate-row: r = g*32 + u
    const int g = r >> 5, u_row = r & 31;
    const bool vrow = (u_row < 24);
    const float* Wx = dir ? wib : wif;
    const float* Wh = dir ? whb : whf;
    const float* bi = dir ? bib : bif;
    const float* bh = dir ? bhb : bhf;
    const int rowW = g * 24 + (vrow ? u_row : 0);
    const float scale = (g == 2) ? TWOLOG2E : -LOG2E;   // g-gate vs i,f,o
    unsigned short vals[8];
    #pragma unroll
    for (int j = 0; j < 8; ++j) {
        const int k = q * 8 + j;
        unsigned short o = 0;
        if (vrow) {
            if (set == 0) {
                if (k < 28) {
                    const int f = (k < 14) ? k : k - 14;
                    o = bf16_rne(scale * Wx[rowW * IN_F + f]);
                } else if (k < 30) {
                    const float b = scale * (bi[rowW] + bh[rowW]);
                    const unsigned short hi = bf16_rne(b);
                    o = (k == 28) ? hi : bf16_rne(b - bf16_to_f(hi));
                }
            } else {
                const int j7 = k & 7, kq = k >> 3;
                const int uh = (j7 < 4) ? kq * 4 + j7 : 16 + kq * 4 + (j7 - 4);
                if (uh < 24) o = bf16_rne(scale * Wh[rowW * H + uh]);
            }
        }
        vals[j] = o;
    }
    unsigned short* d = ws + (size_t)gid * 8;
    #pragma unroll
    for (int j = 0; j < 8; ++j) d[j] = vals[j];
}

__global__ __launch_bounds__(128, 3)
void bilstm_mfma(const float* __restrict__ x, const unsigned short* __restrict__ wpk,
                 const float* __restrict__ head_w, const float* __restrict__ head_b,
                 float* __restrict__ out, int B)
{
    __align__(16) __shared__ unsigned char arena[2 * WAVE_LDS];

    const int tid  = threadIdx.x;
    const int wave = __builtin_amdgcn_readfirstlane(tid >> 6);   // 0 = fwd, 1 = bwd
    const int lane = tid & 63;
    const int q    = lane >> 4;
    const int col  = lane & 15;
    const int b0   = blockIdx.x * 16;

    // resident weight A-fragments: 2 sets x 8 tiles = 64 VGPRs
    frag8 Aw[2][8];
    #pragma unroll
    for (int s = 0; s < 2; ++s)
        #pragma unroll
        for (int t = 0; t < 8; ++t)
            Aw[s][t] = ((const frag8*)wpk)[((wave * 2 + s) * 8 + t) * 64 + lane];

    unsigned char* xbase = arena + wave * WAVE_LDS;

    // stage one (step, elem) x B-frag: k 0..13 = x_hi (trunc), 14..27 = x_lo,
    // 28..29 = 1.0 (bias rows in A), 30..31 = 0
    auto stage_x = [&](int si, int e) {
        const int t = wave ? (T_STEPS - 1 - si) : si;
        const float* xr = x + ((size_t)(b0 + e) * T_STEPS + t) * IN_F;
        unsigned int xu[IN_F];
        #pragma unroll
        for (int i = 0; i < 7; ++i) {
            f2 v = *(const f2*)(xr + 2 * i);
            xu[2*i] = __float_as_uint(v.x); xu[2*i+1] = __float_as_uint(v.y);
        }
        unsigned int lo[IN_F];
        #pragma unroll
        for (int i = 0; i < IN_F; ++i)
            lo[i] = __float_as_uint(__uint_as_float(xu[i])
                                    - __uint_as_float(xu[i] & 0xFFFF0000u));
        unsigned int w[16];
        #pragma unroll
        for (int i = 0; i < 7; ++i)
            w[i] = __builtin_amdgcn_perm(xu[2*i+1], xu[2*i], 0x07060302u);   // {hi16,hi16}
        w[7] = __builtin_amdgcn_perm(lo[1], lo[0], 0x07060302u);
        #pragma unroll
        for (int i = 0; i < 6; ++i)
            w[8 + i] = __builtin_amdgcn_perm(lo[2*i+3], lo[2*i+2], 0x07060302u);
        w[14] = 0x3F803F80u;   // bf16 {1.0, 1.0} -> bias rows in A
        w[15] = 0u;
        #pragma unroll
        for (int qq = 0; qq < 4; ++qq)
            *(u4*)(xbase + si * 1024 + qq * 256 + e * 16) =
                (u4){w[qq*4], w[qq*4+1], w[qq*4+2], w[qq*4+3]};
    };

    // prefill ALL 13 steps (no restage; wave-private region, no barrier)
    for (int rr = lane; rr < NSTEP * 16; rr += 64) stage_x(rr >> 4, rr & 15);

    float c_st[2][4];
    #pragma unroll
    for (int p = 0; p < 2; ++p)
        #pragma unroll
        for (int r = 0; r < 4; ++r) c_st[p][r] = 0.0f;

    float hv[2][4];        // this lane's h: units 4q+r (p=0), 16+4q+r (p=1)
    frag8 Bhh, Bhl;        // recurrent h as B-fragments — registers only
    const f4 zc = {0.f, 0.f, 0.f, 0.f};

    const unsigned char* xrd = xbase + q * 256 + col * 16;

    // gates: acc tiles (i,f,g,o) = (p, 2+p, 4+p, 6+p); lane batch = col
    auto gates = [&](f4* acc) {
        float hl[2][4];
        #pragma unroll
        for (int p = 0; p < 2; ++p) {
            #pragma unroll
            for (int r = 0; r < 4; ++r) {
                const float ig = fast_rcp(1.0f + EXP2F(acc[0 + p][r]));
                const float fg = fast_rcp(1.0f + EXP2F(acc[2 + p][r]));
                const float gg = 1.0f - 2.0f * fast_rcp(1.0f + EXP2F(acc[4 + p][r]));
                const float og = fast_rcp(1.0f + EXP2F(acc[6 + p][r]));
                const float cn = fg * c_st[p][r] + ig * gg;
                c_st[p][r] = cn;
                const float tc = 1.0f - 2.0f * fast_rcp(1.0f + EXP2F(TWOLOG2E * cn));
                const float h  = og * tc;
                hv[p][r] = h;
                hl[p][r] = h - __uint_as_float(__float_as_uint(h) & 0xFFFF0000u);
            }
        }
        // pack own h -> own B-frag: k order [p0 r0..r3, p1 r0..r3]
        const u4 uh4 = {
            __builtin_amdgcn_perm(__float_as_uint(hv[0][1]), __float_as_uint(hv[0][0]), 0x07060302u),
            __builtin_amdgcn_perm(__float_as_uint(hv[0][3]), __float_as_uint(hv[0][2]), 0x07060302u),
            __builtin_amdgcn_perm(__float_as_uint(hv[1][1]), __float_as_uint(hv[1][0]), 0x07060302u),
            __builtin_amdgcn_perm(__float_as_uint(hv[1][3]), __float_as_uint(hv[1][2]), 0x07060302u)};
        const u4 ul4 = {
            __builtin_amdgcn_perm(__float_as_uint(hl[0][1]), __float_as_uint(hl[0][0]), 0x07060302u),
            __builtin_amdgcn_perm(__float_as_uint(hl[0][3]), __float_as_uint(hl[0][2]), 0x07060302u),
            __builtin_amdgcn_perm(__float_as_uint(hl[1][1]), __float_as_uint(hl[1][0]), 0x07060302u),
            __builtin_amdgcn_perm(__float_as_uint(hl[1][3]), __float_as_uint(hl[1][2]), 0x07060302u)};
        Bhh = __builtin_bit_cast(frag8, uh4);
        Bhl = __builtin_bit_cast(frag8, ul4);
    };

    // ---- step 0 (h = 0: x-product + bias rows only) ----
    {
        const frag8 Bx = *(const frag8*)(xrd);
        f4 acc[8];
        #pragma unroll
        for (int t = 0; t < 8; ++t)
            acc[t] = __builtin_amdgcn_mfma_f32_16x16x32_bf16(Aw[0][t], Bx, zc, 0, 0, 0);
        gates(acc);
    }

    // ---- steps 1..12: pure-register recurrence, zero DS ops on the h path ----
    #pragma unroll 1
    for (int s = 1; s < NSTEP; ++s) {
        const frag8 Bx = *(const frag8*)(xrd + s * 1024);
        f4 acc[8];
        #pragma unroll
        for (int t = 0; t < 8; ++t) {
            acc[t] = __builtin_amdgcn_mfma_f32_16x16x32_bf16(Aw[0][t], Bx,  zc,     0, 0, 0);
            acc[t] = __builtin_amdgcn_mfma_f32_16x16x32_bf16(Aw[1][t], Bhh, acc[t], 0, 0, 0);
            acc[t] = __builtin_amdgcn_mfma_f32_16x16x32_bf16(Aw[1][t], Bhl, acc[t], 0, 0, 0);
        }
        gates(acc);
    }

    // final h (fp32) -> own LDS region (x staging is dead); units: p0 = 4q+r, p1 = 16+4q+r
    *(f4*)(xbase + col * 96 + q * 16) = (f4){hv[0][0], hv[0][1], hv[0][2], hv[0][3]};
    if (q < 2)   // p1 units 16+4q+r valid only for q<2 (u<24); q>=2 are pad
        *(f4*)(xbase + col * 96 + 64 + q * 16) = (f4){hv[1][0], hv[1][1], hv[1][2], hv[1][3]};

    __syncthreads();   // only cross-wave point: head reads both directions' h

    if (tid < 64) {
        const int e = tid >> 2, cls = tid & 3;
        float acc = head_b[cls];
        const float* hf = (const float*)(arena + e * 96);              // fwd
        const float* hb = (const float*)(arena + WAVE_LDS + e * 96);   // bwd
        #pragma unroll
        for (int u = 0; u < H; ++u)
            acc += hf[u] * head_w[cls * 2 * H + u] + hb[u] * head_w[cls * 2 * H + H + u];
        out[(size_t)b0 * 4 + tid] = acc;
    }
}

extern "C" void kernel_launch(void* const* d_in, const int* in_sizes, int n_in,
                              void* d_out, int out_size, void* d_ws, size_t ws_size,
                              hipStream_t stream)
{
    const float* x      = (const float*)d_in[0];
    const float* w_ih_f = (const float*)d_in[1];
    const float* w_hh_f = (const float*)d_in[2];
    const float* b_ih_f = (const float*)d_in[3];
    const float* b_hh_f = (const float*)d_in[4];
    const float* w_ih_b = (const float*)d_in[5];
    const float* w_hh_b = (const float*)d_in[6];
    const float* b_ih_b = (const float*)d_in[7];
    const float* b_hh_b = (const float*)d_in[8];
    const float* head_w = (const float*)d_in[9];
    const float* head_b = (const float*)d_in[10];
    float* out = (float*)d_out;
    unsigned short* ws = (unsigned short*)d_ws;

    const int B = in_sizes[0] / (T_STEPS * IN_F);

    hipLaunchKernelGGL(pack_mfma, dim3(8), dim3(256), 0, stream,
                       w_ih_f, w_hh_f, b_ih_f, b_hh_f,
                       w_ih_b, w_hh_b, b_ih_b, b_hh_b, ws);
    hipLaunchKernelGGL(bilstm_mfma, dim3((B + 15) / 16), dim3(128), 0, stream,
                       x, ws, head_w, head_b, out, B);
}

// Round 8
// 177.801 us; speedup vs baseline: 2.3006x; 1.1133x over previous
//
#include <hip/hip_runtime.h>

typedef __attribute__((ext_vector_type(8))) short frag8;     // 8 bf16 = 4 VGPRs
typedef __attribute__((ext_vector_type(4))) float f4;
typedef __attribute__((ext_vector_type(4))) unsigned int u4;
typedef __attribute__((ext_vector_type(2))) float f2;

namespace {
constexpr int T_STEPS = 25;
constexpr int IN_F    = 14;
constexpr int H       = 24;
constexpr int NSTEP   = 13;
constexpr int WAVE_LDS = NSTEP * 1024;   // 13312 B per wave: x staging only
// Pad-free M=96 layout (6 tiles of 16 rows):
//   tile t<4, row m      -> gate t,   unit m        (m = 0..15)
//   tile 4,  row m       -> gate m&3, unit 16+(m>>2)
//   tile 5,  row m       -> gate m&3, unit 20+(m>>2)
// C/D lane (q=lane>>4, col=lane&15) holds rows m=4q+r -> all 4 gates of units
// {4q+r (r=0..3), 16+q, 20+q} = 6 real units, no padding.
// Wh B-operand k-slot map (k = 8q'+j): j<4 -> unit 4q'+j; j=4 -> 16+q';
// j=5 -> 20+q'; j>=6 -> zero. A lane's OUTPUT units == its own B k-slots
// -> recurrent h stays in registers.
// d_ws: shorts [0..12288): frags ((dir*2+set)*6+tile)*64+lane, 8 shorts.
//   Pre-scaled per gate: i,f,o rows * (-log2e), g rows * (2*log2e).
//   set 0 = Wx: k 0..13 = Wx[f] (x_hi), 14..27 = Wx[f-14] (x_lo),
//           k 28 = bias_hi, 29 = bias_lo, 30..31 = 0
//   set 1 = Wh: k-map above
constexpr float LOG2E    = 1.4426950408889634f;
constexpr float TWOLOG2E = 2.8853900817779268f;
}

#if __has_builtin(__builtin_amdgcn_exp2f)
#define EXP2F(v) __builtin_amdgcn_exp2f(v)
#else
#define EXP2F(v) __expf(0.6931471805599453f * (v))
#endif

__device__ __forceinline__ unsigned short bf16_rne(float f) {
    unsigned int u = __float_as_uint(f);
    u += 0x7fff + ((u >> 16) & 1);
    return (unsigned short)(u >> 16);
}
__device__ __forceinline__ float bf16_to_f(unsigned short s) {
    return __uint_as_float(((unsigned int)s) << 16);
}
__device__ __forceinline__ float fast_rcp(float x) { return __builtin_amdgcn_rcpf(x); }

__global__ void pack_mfma(const float* __restrict__ wif, const float* __restrict__ whf,
                          const float* __restrict__ bif, const float* __restrict__ bhf,
                          const float* __restrict__ wib, const float* __restrict__ whb,
                          const float* __restrict__ bib, const float* __restrict__ bhb,
                          unsigned short* __restrict__ ws)
{
    const int gid = blockIdx.x * 256 + threadIdx.x;
    if (gid >= 1536) return;                 // 2 dir * 2 sets * 6 tiles * 64 lanes
    const int lane = gid & 63;
    const int tile = (gid >> 6) % 6;
    const int set  = (gid / 384) & 1;
    const int dir  = gid / 768;
    const int m = lane & 15, q = lane >> 4;  // A-frag: row-in-tile m, k = q*8+j
    // row -> (gate, unit)
    const int g = (tile < 4) ? tile : (m & 3);
    const int u_row = (tile < 4) ? m : ((tile == 4 ? 16 : 20) + (m >> 2));
    const float* Wx = dir ? wib : wif;
    const float* Wh = dir ? whb : whf;
    const float* bi = dir ? bib : bif;
    const float* bh = dir ? bhb : bhf;
    const int rowW = g * 24 + u_row;         // original weight row
    const float scale = (g == 2) ? TWOLOG2E : -LOG2E;   // g-gate vs i,f,o
    unsigned short vals[8];
    #pragma unroll
    for (int j = 0; j < 8; ++j) {
        const int k = q * 8 + j;
        unsigned short o = 0;
        if (set == 0) {
            if (k < 28) {
                const int f = (k < 14) ? k : k - 14;
                o = bf16_rne(scale * Wx[rowW * IN_F + f]);
            } else if (k < 30) {
                const float b = scale * (bi[rowW] + bh[rowW]);
                const unsigned short hi = bf16_rne(b);
                o = (k == 28) ? hi : bf16_rne(b - bf16_to_f(hi));
            }
        } else {
            const int j7 = k & 7, kq = k >> 3;
            int uh = -1;
            if (j7 < 4)       uh = kq * 4 + j7;
            else if (j7 == 4) uh = 16 + kq;
            else if (j7 == 5) uh = 20 + kq;
            if (uh >= 0) o = bf16_rne(scale * Wh[rowW * H + uh]);
        }
        vals[j] = o;
    }
    unsigned short* d = ws + (size_t)gid * 8;
    #pragma unroll
    for (int j = 0; j < 8; ++j) d[j] = vals[j];
}

__global__ __launch_bounds__(128, 3)
void bilstm_mfma(const float* __restrict__ x, const unsigned short* __restrict__ wpk,
                 const float* __restrict__ head_w, const float* __restrict__ head_b,
                 float* __restrict__ out, int B)
{
    __align__(16) __shared__ unsigned char arena[2 * WAVE_LDS];

    const int tid  = threadIdx.x;
    const int wave = __builtin_amdgcn_readfirstlane(tid >> 6);   // 0 = fwd, 1 = bwd
    const int lane = tid & 63;
    const int q    = lane >> 4;
    const int col  = lane & 15;
    const int b0   = blockIdx.x * 16;

    // resident weight A-fragments: 2 sets x 6 tiles = 48 VGPRs
    frag8 Aw[2][6];
    #pragma unroll
    for (int s = 0; s < 2; ++s)
        #pragma unroll
        for (int t = 0; t < 6; ++t)
            Aw[s][t] = ((const frag8*)wpk)[((wave * 2 + s) * 6 + t) * 64 + lane];

    unsigned char* xbase = arena + wave * WAVE_LDS;

    // stage one (step, elem) x B-frag: k 0..13 = x_hi (trunc), 14..27 = x_lo,
    // 28..29 = 1.0 (bias rows in A), 30..31 = 0
    auto stage_x = [&](int si, int e) {
        const int t = wave ? (T_STEPS - 1 - si) : si;
        const float* xr = x + ((size_t)(b0 + e) * T_STEPS + t) * IN_F;
        unsigned int xu[IN_F];
        #pragma unroll
        for (int i = 0; i < 7; ++i) {
            f2 v = *(const f2*)(xr + 2 * i);
            xu[2*i] = __float_as_uint(v.x); xu[2*i+1] = __float_as_uint(v.y);
        }
        unsigned int lo[IN_F];
        #pragma unroll
        for (int i = 0; i < IN_F; ++i)
            lo[i] = __float_as_uint(__uint_as_float(xu[i])
                                    - __uint_as_float(xu[i] & 0xFFFF0000u));
        unsigned int w[16];
        #pragma unroll
        for (int i = 0; i < 7; ++i)
            w[i] = __builtin_amdgcn_perm(xu[2*i+1], xu[2*i], 0x07060302u);   // {hi16,hi16}
        w[7] = __builtin_amdgcn_perm(lo[1], lo[0], 0x07060302u);
        #pragma unroll
        for (int i = 0; i < 6; ++i)
            w[8 + i] = __builtin_amdgcn_perm(lo[2*i+3], lo[2*i+2], 0x07060302u);
        w[14] = 0x3F803F80u;   // bf16 {1.0, 1.0} -> bias rows in A
        w[15] = 0u;
        #pragma unroll
        for (int qq = 0; qq < 4; ++qq)
            *(u4*)(xbase + si * 1024 + qq * 256 + e * 16) =
                (u4){w[qq*4], w[qq*4+1], w[qq*4+2], w[qq*4+3]};
    };

    // prefill ALL 13 steps (wave-private region, no barrier)
    for (int rr = lane; rr < NSTEP * 16; rr += 64) stage_x(rr >> 4, rr & 15);

    f4    cv = {0.f, 0.f, 0.f, 0.f};   // c of units 4q+r
    float c_s[2] = {0.f, 0.f};         // c of units 16+q, 20+q
    f4    Hv;                          // h of units 4q+r (fp32, for head)
    float h_s[2];                      // h of units 16+q, 20+q
    frag8 Bhh, Bhl;                    // recurrent h as B-fragments — registers only
    const f4 zc = {0.f, 0.f, 0.f, 0.f};

    const unsigned char* xrd = xbase + q * 256 + col * 16;

    // gates from acc[6]: vector block (units 4q+r: gate g = acc[g], f4 over r)
    // + 2 scalar units (acc[4],acc[5]: gate g = component g).
    // Pre-scaled accs: i,f,o hold -a*log2e; g holds 2a*log2e.
    // c' = (c*(1+ei)(1+eg) + (eg-1)(1+ef)) * rcp((1+ef)(1+ei)(1+eg))
    // h  = (ec-1) * rcp((1+eo)(1+ec)),  ec = exp2(2c'*log2e)
    auto gates = [&](const f4* acc) {
        f4 EI, EF, EG, EO, EC;
        #pragma unroll
        for (int r = 0; r < 4; ++r) {
            EI[r] = EXP2F(acc[0][r]);
            EF[r] = EXP2F(acc[1][r]);
            EG[r] = EXP2F(acc[2][r]);
            EO[r] = EXP2F(acc[3][r]);
        }
        const f4 P  = (EI + 1.0f) * (EG + 1.0f);
        const f4 Df = P * (EF + 1.0f);
        f4 Rf;
        #pragma unroll
        for (int r = 0; r < 4; ++r) Rf[r] = fast_rcp(Df[r]);
        cv = (cv * P + (EG - 1.0f) * (EF + 1.0f)) * Rf;
        #pragma unroll
        for (int r = 0; r < 4; ++r) EC[r] = EXP2F(TWOLOG2E * cv[r]);
        const f4 Do = (EO + 1.0f) * (EC + 1.0f);
        f4 Ro;
        #pragma unroll
        for (int r = 0; r < 4; ++r) Ro[r] = fast_rcp(Do[r]);
        Hv = (EC - 1.0f) * Ro;

        #pragma unroll
        for (int s = 0; s < 2; ++s) {
            const float ei = EXP2F(acc[4 + s][0]);
            const float ef = EXP2F(acc[4 + s][1]);
            const float eg = EXP2F(acc[4 + s][2]);
            const float eo = EXP2F(acc[4 + s][3]);
            const float P2 = (1.0f + ei) * (1.0f + eg);
            const float cn = (c_s[s] * P2 + (eg - 1.0f) * (1.0f + ef))
                             * fast_rcp(P2 * (1.0f + ef));
            c_s[s] = cn;
            const float ec = EXP2F(TWOLOG2E * cn);
            h_s[s] = (ec - 1.0f) * fast_rcp((1.0f + eo) * (1.0f + ec));
        }

        // pack h -> own B-frag k-slots {8q+j}: j0..3 = units 4q+j, j4 = 16+q,
        // j5 = 20+q, j6..7 = zero-weight slots (any value)
        f4 Hl;
        #pragma unroll
        for (int r = 0; r < 4; ++r)
            Hl[r] = Hv[r] - __uint_as_float(__float_as_uint(Hv[r]) & 0xFFFF0000u);
        const float hl4 = h_s[0] - __uint_as_float(__float_as_uint(h_s[0]) & 0xFFFF0000u);
        const float hl5 = h_s[1] - __uint_as_float(__float_as_uint(h_s[1]) & 0xFFFF0000u);
        const u4 uh4 = {
            __builtin_amdgcn_perm(__float_as_uint(Hv[1]), __float_as_uint(Hv[0]), 0x07060302u),
            __builtin_amdgcn_perm(__float_as_uint(Hv[3]), __float_as_uint(Hv[2]), 0x07060302u),
            __builtin_amdgcn_perm(__float_as_uint(h_s[1]), __float_as_uint(h_s[0]), 0x07060302u),
            0u};
        const u4 ul4 = {
            __builtin_amdgcn_perm(__float_as_uint(Hl[1]), __float_as_uint(Hl[0]), 0x07060302u),
            __builtin_amdgcn_perm(__float_as_uint(Hl[3]), __float_as_uint(Hl[2]), 0x07060302u),
            __builtin_amdgcn_perm(__float_as_uint(hl5), __float_as_uint(hl4), 0x07060302u),
            0u};
        Bhh = __builtin_bit_cast(frag8, uh4);
        Bhl = __builtin_bit_cast(frag8, ul4);
    };

    // ---- step 0 (h = 0: x-product + bias rows only) ----
    {
        const frag8 Bx = *(const frag8*)(xrd);
        f4 acc[6];
        #pragma unroll
        for (int t = 0; t < 6; ++t)
            acc[t] = __builtin_amdgcn_mfma_f32_16x16x32_bf16(Aw[0][t], Bx, zc, 0, 0, 0);
        gates(acc);
    }

    // ---- steps 1..12: pure-register recurrence ----
    #pragma unroll 1
    for (int s = 1; s < NSTEP; ++s) {
        const frag8 Bx = *(const frag8*)(xrd + s * 1024);
        f4 acc[6];
        #pragma unroll
        for (int t = 0; t < 6; ++t) {
            acc[t] = __builtin_amdgcn_mfma_f32_16x16x32_bf16(Aw[0][t], Bx,  zc,     0, 0, 0);
            acc[t] = __builtin_amdgcn_mfma_f32_16x16x32_bf16(Aw[1][t], Bhh, acc[t], 0, 0, 0);
            acc[t] = __builtin_amdgcn_mfma_f32_16x16x32_bf16(Aw[1][t], Bhl, acc[t], 0, 0, 0);
        }
        gates(acc);
    }

    // final h (fp32) -> own LDS region (x staging is dead)
    // unit u of batch-elem col lives at byte col*96 + u*4
    *(f4*)(xbase + col * 96 + q * 16) = Hv;                       // units 4q+r
    *(float*)(xbase + col * 96 + 64 + q * 4) = h_s[0];            // unit 16+q
    *(float*)(xbase + col * 96 + 80 + q * 4) = h_s[1];            // unit 20+q

    __syncthreads();   // only cross-wave point: head reads both directions' h

    if (tid < 64) {
        const int e = tid >> 2, cls = tid & 3;
        float acc = head_b[cls];
        const float* hf = (const float*)(arena + e * 96);              // fwd
        const float* hb = (const float*)(arena + WAVE_LDS + e * 96);   // bwd
        #pragma unroll
        for (int u = 0; u < H; ++u)
            acc += hf[u] * head_w[cls * 2 * H + u] + hb[u] * head_w[cls * 2 * H + H + u];
        out[(size_t)b0 * 4 + tid] = acc;
    }
}

extern "C" void kernel_launch(void* const* d_in, const int* in_sizes, int n_in,
                              void* d_out, int out_size, void* d_ws, size_t ws_size,
                              hipStream_t stream)
{
    const float* x      = (const float*)d_in[0];
    const float* w_ih_f = (const float*)d_in[1];
    const float* w_hh_f = (const float*)d_in[2];
    const float* b_ih_f = (const float*)d_in[3];
    const float* b_hh_f = (const float*)d_in[4];
    const float* w_ih_b = (const float*)d_in[5];
    const float* w_hh_b = (const float*)d_in[6];
    const float* b_ih_b = (const float*)d_in[7];
    const float* b_hh_b = (const float*)d_in[8];
    const float* head_w = (const float*)d_in[9];
    const float* head_b = (const float*)d_in[10];
    float* out = (float*)d_out;
    unsigned short* ws = (unsigned short*)d_ws;

    const int B = in_sizes[0] / (T_STEPS * IN_F);

    hipLaunchKernelGGL(pack_mfma, dim3(6), dim3(256), 0, stream,
                       w_ih_f, w_hh_f, b_ih_f, b_hh_f,
                       w_ih_b, w_hh_b, b_ih_b, b_hh_b, ws);
    hipLaunchKernelGGL(bilstm_mfma, dim3((B + 15) / 16), dim3(128), 0, stream,
                       x, ws, head_w, head_b, out, B);
}